// Round 1
// baseline (6048.194 us; speedup 1.0000x reference)
//
#include <hip/hip_runtime.h>

typedef unsigned int u32;
typedef unsigned short u16;
typedef unsigned long long u64;

typedef __attribute__((ext_vector_type(8))) short bf16x8;
typedef __attribute__((ext_vector_type(4))) float f32x4;

__device__ __forceinline__ u16 f2bf(float f) {
    u32 u = __float_as_uint(f);
    u += 0x7fffu + ((u >> 16) & 1u);
    return (u16)(u >> 16);
}
__device__ __forceinline__ float bf2f(u16 h) {
    return __uint_as_float(((u32)h) << 16);
}

// ---------------------------------------------------------------------------
// prep: convert/transpose weights to bf16, zero h-exchange buffers + flags
// W1T[1200][200], W2T[600][400], U1T[1200][400], U2T[600][200]
// ---------------------------------------------------------------------------
__global__ __launch_bounds__(256) void prep_kernel(
    const float* __restrict__ W1, const float* __restrict__ W2,
    const float* __restrict__ U1, const float* __restrict__ U2,
    u16* __restrict__ W1T, u16* __restrict__ W2T,
    u16* __restrict__ U1T, u16* __restrict__ U2T,
    float* __restrict__ hzero, int* __restrict__ flags)
{
    int i = blockIdx.x * 256 + threadIdx.x;
    if (i < 240000) { int j = i / 200, k = i - j * 200; W1T[i] = f2bf(W1[k * 1200 + j]); return; }
    i -= 240000;
    if (i < 240000) { int j = i / 400, k = i - j * 400; W2T[i] = f2bf(W2[k * 600 + j]); return; }
    i -= 240000;
    if (i < 480000) { int j = i / 400, k = i - j * 400; U1T[i] = f2bf(U1[k * 1200 + j]); return; }
    i -= 480000;
    if (i < 120000) { int j = i / 200, k = i - j * 200; U2T[i] = f2bf(U2[k * 600 + j]); return; }
    i -= 120000;
    if (i < 153600) { hzero[i] = 0.f; return; }
    i -= 153600;
    if (i < 256) flags[i] = 0;
}

// ---------------------------------------------------------------------------
// embed + batchnorm -> x bf16, layout [t*128 + b][200]
// ---------------------------------------------------------------------------
__global__ __launch_bounds__(256) void embed_bn_kernel(
    const int* __restrict__ tokens, const float* __restrict__ emb,
    const float* __restrict__ gamma, const float* __restrict__ beta,
    const float* __restrict__ mmean, const float* __restrict__ mvar,
    u16* __restrict__ x)
{
    int gid = blockIdx.x * 256 + threadIdx.x;  // 6,553,600 total
    int r = gid / 200, e = gid - r * 200;
    int t = r >> 7, b = r & 127;               // r = t*128 + b
    int tok = tokens[b * 256 + t];
    float v = (emb[(size_t)tok * 200 + e] - mmean[e]) *
              (1.0f / sqrtf(mvar[e] + 1e-3f)) * gamma[e] + beta[e];
    x[gid] = f2bf(v);
}

// ---------------------------------------------------------------------------
// GEMM: C[M][N] (bf16) = A[M][KEL] (bf16) @ B[KEL][N] + bias, B given as
// BT[N][KEL]. Tile 64x64 per 256-thread WG; MFMA 16x16x32 bf16.
// ---------------------------------------------------------------------------
template<int KEL, int KSTEPS, int KPAD>
__global__ __launch_bounds__(256) void gemm_bias_kernel(
    const u16* __restrict__ A, const u16* __restrict__ BT,
    const float* __restrict__ bias, u16* __restrict__ C, int N)
{
    __shared__ u16 A_lds[64 * KPAD];
    __shared__ u16 B_lds[64 * KPAD];
    const int m0 = blockIdx.x * 64, n0 = blockIdx.y * 64;
    const int tid = threadIdx.x;
    const int lane = tid & 63, wave = tid >> 6;
    const int l15 = lane & 15, lq = lane >> 4;

    for (int idx = tid; idx < 64 * (KPAD / 2); idx += 256) {
        int row = idx / (KPAD / 2), kp = idx % (KPAD / 2);
        int k = kp * 2;
        u32 va = (k < KEL) ? *(const u32*)(A + (size_t)(m0 + row) * KEL + k) : 0u;
        *(u32*)(A_lds + row * KPAD + k) = va;
        int gn = n0 + row;
        u32 vb = (k < KEL && gn < N) ? *(const u32*)(BT + (size_t)gn * KEL + k) : 0u;
        *(u32*)(B_lds + row * KPAD + k) = vb;
    }
    __syncthreads();

    f32x4 acc[4];
    for (int i = 0; i < 4; ++i) acc[i] = (f32x4){0.f, 0.f, 0.f, 0.f};
    for (int ks = 0; ks < KSTEPS; ++ks) {
        bf16x8 a = *(const bf16x8*)(A_lds + (wave * 16 + l15) * KPAD + ks * 32 + lq * 8);
        for (int nt = 0; nt < 4; ++nt) {
            bf16x8 b = *(const bf16x8*)(B_lds + (nt * 16 + l15) * KPAD + ks * 32 + lq * 8);
            acc[nt] = __builtin_amdgcn_mfma_f32_16x16x32_bf16(a, b, acc[nt], 0, 0, 0);
        }
    }
    for (int nt = 0; nt < 4; ++nt) {
        int col = n0 + nt * 16 + l15;
        if (col < N) {
            float bv = bias[col];
            for (int i = 0; i < 4; ++i) {
                int row = m0 + wave * 16 + lq * 4 + i;
                C[(size_t)row * N + col] = f2bf(acc[nt][i] + bv);
            }
        }
    }
}

// ---------------------------------------------------------------------------
// Persistent GRU scan. 8 batch-groups of 16; each group split over G WGs by
// h-index. U-slice (bf16) LDS-resident. Per-step h exchange via device-scope
// atomics + parity double buffer + per-WG flags (flag = #published steps).
// ---------------------------------------------------------------------------
template<int UH, int G, int KSTEPS, int KPAD, int HS, int NC, int NCP, int NT,
         int MAXT, bool WB16>
__global__ __launch_bounds__(256) void gru_kernel(
    const u16* __restrict__ xw,      // [256*128][3*UH] bf16 (row = t*128+b)
    const u16* __restrict__ UT,      // [3*UH][UH] bf16 (transposed U)
    const float* __restrict__ br,    // [3*UH] recurrent bias
    const int* __restrict__ tokens,  // [128][256]
    float* __restrict__ out_f32,     // [128][256][UH]
    u16* __restrict__ out_b16,       // [256*128][UH] or unused
    float* __restrict__ h_final,     // [128][UH]
    float* __restrict__ hbuf,        // [8][2][16][UH] fp32
    int* __restrict__ flags)         // [8][G]
{
    __shared__ u16 U_lds[NCP * KPAD];
    __shared__ u16 h_lds[16 * KPAD];
    __shared__ float rec_lds[16 * NCP];

    const int wg = blockIdx.x;
    const int g = wg / G, w = wg % G;
    const int tid = threadIdx.x;
    const int b0 = g * 16;
    const int lane = tid & 63, wave = tid >> 6;
    const int l15 = lane & 15, lq = lane >> 4;

    // zero LDS (zero-padding of K and column tails)
    for (int i = tid; i < NCP * KPAD / 2; i += 256) ((u32*)U_lds)[i] = 0u;
    for (int i = tid; i < 16 * KPAD / 2; i += 256) ((u32*)h_lds)[i] = 0u;
    __syncthreads();
    // stage U-slice: local col c -> global col j = (c/HS)*UH + w*HS + (c%HS)
    for (int idx = tid; idx < NC * (UH / 2); idx += 256) {
        int c = idx / (UH / 2), kp = idx % (UH / 2);
        int j = (c / HS) * UH + w * HS + (c % HS);
        u32 v = *(const u32*)(UT + (size_t)j * UH + kp * 2);
        *(u32*)(U_lds + c * KPAD + kp * 2) = v;
    }

    float* hb = hbuf + (size_t)g * 2 * 16 * UH;
    int* fl = flags + g * G;

    for (int t = 0; t < 256; ++t) {
        // 1. wait for all peers to have published h_{t-1}
        if (tid < G) {
            while (__hip_atomic_load(fl + tid, __ATOMIC_RELAXED,
                                     __HIP_MEMORY_SCOPE_AGENT) < t) { }
        }
        __syncthreads();
        const float* hsrc = hb + ((t + 1) & 1) * 16 * UH;
        float* hdst = hb + (t & 1) * 16 * UH;
        // 2. stage h_{t-1} (fp32 -> bf16) into LDS
        for (int i = tid; i < 16 * (UH / 2); i += 256) {
            int b = i / (UH / 2), kp = i % (UH / 2);
            u64 v2 = __hip_atomic_load((const u64*)(hsrc + b * UH + kp * 2),
                                       __ATOMIC_RELAXED, __HIP_MEMORY_SCOPE_AGENT);
            float f0 = __uint_as_float((u32)v2);
            float f1 = __uint_as_float((u32)(v2 >> 32));
            u32 pk = (u32)f2bf(f0) | ((u32)f2bf(f1) << 16);
            *(u32*)(h_lds + b * KPAD + kp * 2) = pk;
        }
        __syncthreads();
        // 3. rec = h @ U-slice  (MFMA 16x16x32)
        f32x4 acc[MAXT];
        for (int ti = 0; ti < MAXT; ++ti) acc[ti] = (f32x4){0.f, 0.f, 0.f, 0.f};
        for (int ks = 0; ks < KSTEPS; ++ks) {
            bf16x8 a = *(const bf16x8*)(h_lds + l15 * KPAD + ks * 32 + lq * 8);
            int ti = 0;
            for (int nt = wave; nt < NT; nt += 4, ++ti) {
                bf16x8 b = *(const bf16x8*)(U_lds + (nt * 16 + l15) * KPAD + ks * 32 + lq * 8);
                acc[ti] = __builtin_amdgcn_mfma_f32_16x16x32_bf16(a, b, acc[ti], 0, 0, 0);
            }
        }
        {
            int ti = 0;
            for (int nt = wave; nt < NT; nt += 4, ++ti)
                for (int i = 0; i < 4; ++i)
                    rec_lds[(lq * 4 + i) * NCP + nt * 16 + l15] = acc[ti][i];
        }
        __syncthreads();
        // 4. gates + state update + outputs + publish
        for (int u = tid; u < 16 * HS; u += 256) {
            int b = u / HS, co = u % HS;
            int ih = w * HS + co;
            int gb = b0 + b;
            const u16* xrow = xw + (size_t)(t * 128 + gb) * (3 * UH);
            float xz = bf2f(xrow[ih]);
            float xr = bf2f(xrow[UH + ih]);
            float xh = bf2f(xrow[2 * UH + ih]);
            float rz = rec_lds[b * NCP + co] + br[ih];
            float rr = rec_lds[b * NCP + HS + co] + br[UH + ih];
            float rh = rec_lds[b * NCP + 2 * HS + co] + br[2 * UH + ih];
            float hold = __hip_atomic_load(hsrc + b * UH + ih, __ATOMIC_RELAXED,
                                           __HIP_MEMORY_SCOPE_AGENT);
            float z = 1.f / (1.f + __expf(-(xz + rz)));
            float r = 1.f / (1.f + __expf(-(xr + rr)));
            float pre = xh + r * rh;
            float th = 2.f / (1.f + __expf(-2.f * pre)) - 1.f;
            float hn = z * hold + (1.f - z) * th;
            if (tokens[gb * 256 + t] == 0) hn = hold;   // masked: carry state
            out_f32[((size_t)gb * 256 + t) * UH + ih] = hn;
            if (WB16) out_b16[(size_t)(t * 128 + gb) * UH + ih] = f2bf(hn);
            if (t == 255) h_final[(size_t)gb * UH + ih] = hn;
            __hip_atomic_store(hdst + b * UH + ih, hn, __ATOMIC_RELAXED,
                               __HIP_MEMORY_SCOPE_AGENT);
        }
        __syncthreads();
        if (tid == 0)
            __hip_atomic_store(fl + w, t + 1, __ATOMIC_RELEASE,
                               __HIP_MEMORY_SCOPE_AGENT);
    }
}

// ---------------------------------------------------------------------------
// launch
// ---------------------------------------------------------------------------
extern "C" void kernel_launch(void* const* d_in, const int* in_sizes, int n_in,
                              void* d_out, int out_size, void* d_ws, size_t ws_size,
                              hipStream_t stream)
{
    const int*   tokens = (const int*)d_in[0];
    const float* emb    = (const float*)d_in[1];
    const float* gamma  = (const float*)d_in[2];
    const float* beta   = (const float*)d_in[3];
    const float* mmean  = (const float*)d_in[4];
    const float* mvar   = (const float*)d_in[5];
    const float* W1     = (const float*)d_in[6];
    const float* U1     = (const float*)d_in[7];
    const float* b1     = (const float*)d_in[8];
    const float* W2     = (const float*)d_in[9];
    const float* U2     = (const float*)d_in[10];
    const float* b2     = (const float*)d_in[11];

    float* out = (float*)d_out;
    char* ws = (char*)d_ws;

    u16* x     = (u16*)(ws + 0);            // 32768*200*2  = 13,107,200
    u16* xw1   = (u16*)(ws + 13107200);     // 32768*1200*2 = 78,643,200
    u16* o1b   = (u16*)(ws + 91750400);     // 32768*400*2  = 26,214,400
    u16* xw2   = (u16*)(ws + 117964800);    // 32768*600*2  = 39,321,600
    u16* W1T   = (u16*)(ws + 157286400);    // 480,000
    u16* W2T   = (u16*)(ws + 157766400);    // 480,000
    u16* U1T   = (u16*)(ws + 158246400);    // 960,000
    u16* U2T   = (u16*)(ws + 159206400);    // 240,000
    float* hbuf1 = (float*)(ws + 159446400);// 102,400 floats = 409,600 B
    float* hbuf2 = (float*)(ws + 159856000);// 51,200 floats  = 204,800 B
    int* flags   = (int*)(ws + 160060800);  // 256 ints

    float* out2 = out;              // [128,256,200]
    float* out1 = out + 6553600;    // [128,256,400]
    float* h2   = out + 19660800;   // [128,200]
    float* h1   = out + 19686400;   // [128,400]

    prep_kernel<<<4820, 256, 0, stream>>>(W1, W2, U1, U2, W1T, W2T, U1T, U2T,
                                          hbuf1, flags);
    embed_bn_kernel<<<25600, 256, 0, stream>>>(tokens, emb, gamma, beta, mmean,
                                               mvar, x);
    // xw1 = x @ W1 + bi1   ([32768,200]@[200,1200])
    gemm_bias_kernel<200, 7, 232><<<dim3(512, 19), 256, 0, stream>>>(
        x, W1T, b1, xw1, 1200);
    // GRU1: UH=400, G=16 (128 WGs), KSTEPS=13, KPAD=424, HS=25, NC=75, NCP=80,
    // NT=5, MAXT=2, write bf16 copy of out1
    gru_kernel<400, 16, 13, 424, 25, 75, 80, 5, 2, true><<<128, 256, 0, stream>>>(
        xw1, U1T, b1 + 1200, tokens, out1, o1b, h1, hbuf1, flags);
    // xw2 = out1 @ W2 + bi2   ([32768,400]@[400,600])
    gemm_bias_kernel<400, 13, 424><<<dim3(512, 10), 256, 0, stream>>>(
        o1b, W2T, b2, xw2, 600);
    // GRU2: UH=200, G=4 (32 WGs), KSTEPS=7, KPAD=232, HS=50, NC=150, NCP=160,
    // NT=10, MAXT=3
    gru_kernel<200, 4, 7, 232, 50, 150, 160, 10, 3, false><<<32, 256, 0, stream>>>(
        xw2, U2T, b2 + 600, tokens, out2, (u16*)nullptr, h2, hbuf2, flags + 128);
}

// Round 2
// 4553.385 us; speedup vs baseline: 1.3283x; 1.3283x over previous
//
#include <hip/hip_runtime.h>

typedef unsigned int u32;
typedef unsigned short u16;
typedef unsigned long long u64;

typedef __attribute__((ext_vector_type(8))) short bf16x8;
typedef __attribute__((ext_vector_type(4))) float f32x4;

__device__ __forceinline__ u16 f2bf(float f) {
    u32 u = __float_as_uint(f);
    u += 0x7fffu + ((u >> 16) & 1u);
    return (u16)(u >> 16);
}
__device__ __forceinline__ float bf2f(u16 h) {
    return __uint_as_float(((u32)h) << 16);
}

// ---------------------------------------------------------------------------
// prep: convert/transpose weights to bf16, zero h-exchange buffers + counters
// ---------------------------------------------------------------------------
__global__ __launch_bounds__(256) void prep_kernel(
    const float* __restrict__ W1, const float* __restrict__ W2,
    const float* __restrict__ U1, const float* __restrict__ U2,
    u16* __restrict__ W1T, u16* __restrict__ W2T,
    u16* __restrict__ U1T, u16* __restrict__ U2T,
    u32* __restrict__ hzero, int* __restrict__ flags)
{
    int i = blockIdx.x * 256 + threadIdx.x;
    if (i < 240000) { int j = i / 200, k = i - j * 200; W1T[i] = f2bf(W1[k * 1200 + j]); return; }
    i -= 240000;
    if (i < 240000) { int j = i / 400, k = i - j * 400; W2T[i] = f2bf(W2[k * 600 + j]); return; }
    i -= 240000;
    if (i < 480000) { int j = i / 400, k = i - j * 400; U1T[i] = f2bf(U1[k * 1200 + j]); return; }
    i -= 480000;
    if (i < 120000) { int j = i / 200, k = i - j * 200; U2T[i] = f2bf(U2[k * 600 + j]); return; }
    i -= 120000;
    if (i < 76800) { hzero[i] = 0u; return; }   // both bf16 h-exchange buffers
    i -= 76800;
    if (i < 256) flags[i] = 0;
}

// ---------------------------------------------------------------------------
// embed + batchnorm -> x bf16, layout [t*128 + b][200]
// ---------------------------------------------------------------------------
__global__ __launch_bounds__(256) void embed_bn_kernel(
    const int* __restrict__ tokens, const float* __restrict__ emb,
    const float* __restrict__ gamma, const float* __restrict__ beta,
    const float* __restrict__ mmean, const float* __restrict__ mvar,
    u16* __restrict__ x)
{
    int gid = blockIdx.x * 256 + threadIdx.x;  // 6,553,600 total
    int r = gid / 200, e = gid - r * 200;
    int t = r >> 7, b = r & 127;               // r = t*128 + b
    int tok = tokens[b * 256 + t];
    float v = (emb[(size_t)tok * 200 + e] - mmean[e]) *
              (1.0f / sqrtf(mvar[e] + 1e-3f)) * gamma[e] + beta[e];
    x[gid] = f2bf(v);
}

// ---------------------------------------------------------------------------
// GEMM: C[M][N] (bf16) = A[M][KEL] (bf16) @ B[KEL][N] + bias, B given as
// BT[N][KEL]. Tile 64x64 per 256-thread WG; MFMA 16x16x32 bf16.
// ---------------------------------------------------------------------------
template<int KEL, int KSTEPS, int KPAD>
__global__ __launch_bounds__(256) void gemm_bias_kernel(
    const u16* __restrict__ A, const u16* __restrict__ BT,
    const float* __restrict__ bias, u16* __restrict__ C, int N)
{
    __shared__ u16 A_lds[64 * KPAD];
    __shared__ u16 B_lds[64 * KPAD];
    const int m0 = blockIdx.x * 64, n0 = blockIdx.y * 64;
    const int tid = threadIdx.x;
    const int lane = tid & 63, wave = tid >> 6;
    const int l15 = lane & 15, lq = lane >> 4;

    for (int idx = tid; idx < 64 * (KPAD / 2); idx += 256) {
        int row = idx / (KPAD / 2), kp = idx % (KPAD / 2);
        int k = kp * 2;
        u32 va = (k < KEL) ? *(const u32*)(A + (size_t)(m0 + row) * KEL + k) : 0u;
        *(u32*)(A_lds + row * KPAD + k) = va;
        int gn = n0 + row;
        u32 vb = (k < KEL && gn < N) ? *(const u32*)(BT + (size_t)gn * KEL + k) : 0u;
        *(u32*)(B_lds + row * KPAD + k) = vb;
    }
    __syncthreads();

    f32x4 acc[4];
    for (int i = 0; i < 4; ++i) acc[i] = (f32x4){0.f, 0.f, 0.f, 0.f};
    for (int ks = 0; ks < KSTEPS; ++ks) {
        bf16x8 a = *(const bf16x8*)(A_lds + (wave * 16 + l15) * KPAD + ks * 32 + lq * 8);
        for (int nt = 0; nt < 4; ++nt) {
            bf16x8 b = *(const bf16x8*)(B_lds + (nt * 16 + l15) * KPAD + ks * 32 + lq * 8);
            acc[nt] = __builtin_amdgcn_mfma_f32_16x16x32_bf16(a, b, acc[nt], 0, 0, 0);
        }
    }
    for (int nt = 0; nt < 4; ++nt) {
        int col = n0 + nt * 16 + l15;
        if (col < N) {
            float bv = bias[col];
            for (int i = 0; i < 4; ++i) {
                int row = m0 + wave * 16 + lq * 4 + i;
                C[(size_t)row * N + col] = f2bf(acc[nt][i] + bv);
            }
        }
    }
}

// ---------------------------------------------------------------------------
// Persistent GRU scan. 8 batch-groups of 16; each group split over G WGs by
// h-index. U-slice (bf16) LDS-resident. Per-step bf16 h exchange via relaxed
// agent atomics; ordering = s_waitcnt vmcnt(0) + per-group counter fetch_add.
// hold state lives in registers (thread<->element map is step-invariant).
// ---------------------------------------------------------------------------
template<int UH, int G, int KSTEPS, int KPAD, int HS, int NC, int NCP, int NT,
         int MAXT, int MAXE, bool WB16>
__global__ __launch_bounds__(256) void gru_kernel(
    const u16* __restrict__ xw,      // [256*128][3*UH] bf16 (row = t*128+b)
    const u16* __restrict__ UT,      // [3*UH][UH] bf16 (transposed U)
    const float* __restrict__ br,    // [3*UH] recurrent bias
    const int* __restrict__ tokens,  // [128][256]
    float* __restrict__ out_f32,     // [128][256][UH]
    u16* __restrict__ out_b16,       // [256*128][UH] or unused
    float* __restrict__ h_final,     // [128][UH]
    u16* __restrict__ hbuf,          // [8][2][16][UH] bf16
    int* __restrict__ cnt)           // [8] counters spaced 16 ints apart
{
    __shared__ u16 U_lds[NCP * KPAD];
    __shared__ u16 h_lds[16 * KPAD];
    __shared__ float rec_lds[16 * NCP];

    const int wg = blockIdx.x;
    const int g = wg / G, w = wg % G;
    const int tid = threadIdx.x;
    const int b0 = g * 16;
    const int lane = tid & 63, wave = tid >> 6;
    const int l15 = lane & 15, lq = lane >> 4;

    // zero LDS (zero-padding of K and column tails)
    for (int i = tid; i < NCP * KPAD / 2; i += 256) ((u32*)U_lds)[i] = 0u;
    for (int i = tid; i < 16 * KPAD / 2; i += 256) ((u32*)h_lds)[i] = 0u;
    __syncthreads();
    // stage U-slice: local col c -> global col j = (c/HS)*UH + w*HS + (c%HS)
    for (int idx = tid; idx < NC * (UH / 2); idx += 256) {
        int c = idx / (UH / 2), kp = idx % (UH / 2);
        int j = (c / HS) * UH + w * HS + (c % HS);
        u32 v = *(const u32*)(UT + (size_t)j * UH + kp * 2);
        *(u32*)(U_lds + c * KPAD + kp * 2) = v;
    }

    // per-thread gate-element mapping (step-invariant)
    int ne = 0;
    int eb[MAXE], eco[MAXE], eih[MAXE], egb[MAXE], exwoff[MAXE];
    float ebrz[MAXE], ebrr[MAXE], ebrh[MAXE], hold[MAXE];
    for (int u = tid; u < 16 * HS; u += 256) {
        int b = u / HS, co = u % HS;
        int ih = w * HS + co;
        eb[ne] = b; eco[ne] = co; eih[ne] = ih; egb[ne] = b0 + b;
        exwoff[ne] = (b0 + b) * 3 * UH;
        ebrz[ne] = br[ih]; ebrr[ne] = br[UH + ih]; ebrh[ne] = br[2 * UH + ih];
        hold[ne] = 0.f;
        ++ne;
    }

    u16* hb = hbuf + (size_t)g * 2 * 16 * UH;
    int* c = cnt + g * 16;

    for (int t = 0; t < 256; ++t) {
        // 1. gate: wait until all G peers have published h_{t-1}
        if (tid == 0) {
            while (__hip_atomic_load(c, __ATOMIC_RELAXED,
                                     __HIP_MEMORY_SCOPE_AGENT) < t * G)
                __builtin_amdgcn_s_sleep(1);
        }
        __syncthreads();

        // 2a. prefetch gate inputs for this step (independent of h)
        float xzv[MAXE], xrv[MAXE], xhv[MAXE];
        int tokv[MAXE];
        for (int e = 0; e < ne; ++e) {
            const u16* xrow = xw + (size_t)t * (128 * 3 * UH) + exwoff[e];
            xzv[e] = bf2f(xrow[eih[e]]);
            xrv[e] = bf2f(xrow[UH + eih[e]]);
            xhv[e] = bf2f(xrow[2 * UH + eih[e]]);
            tokv[e] = tokens[egb[e] * 256 + t];
        }

        const u16* hsrc = hb + ((t + 1) & 1) * 16 * UH;
        u16* hdst = hb + (t & 1) * 16 * UH;
        // 2b. stage h_{t-1} (bf16) into LDS, 8B chunks
        for (int i = tid; i < 16 * (UH / 4); i += 256) {
            int b = i / (UH / 4), k4 = i % (UH / 4);
            u64 v = __hip_atomic_load((const u64*)(hsrc + b * UH + k4 * 4),
                                      __ATOMIC_RELAXED, __HIP_MEMORY_SCOPE_AGENT);
            *(u64*)(h_lds + b * KPAD + k4 * 4) = v;
        }
        __syncthreads();

        // 3. rec = h @ U-slice  (MFMA 16x16x32)
        f32x4 acc[MAXT];
        for (int ti = 0; ti < MAXT; ++ti) acc[ti] = (f32x4){0.f, 0.f, 0.f, 0.f};
        for (int ks = 0; ks < KSTEPS; ++ks) {
            bf16x8 a = *(const bf16x8*)(h_lds + l15 * KPAD + ks * 32 + lq * 8);
            int ti = 0;
            for (int nt = wave; nt < NT; nt += 4, ++ti) {
                bf16x8 b = *(const bf16x8*)(U_lds + (nt * 16 + l15) * KPAD + ks * 32 + lq * 8);
                acc[ti] = __builtin_amdgcn_mfma_f32_16x16x32_bf16(a, b, acc[ti], 0, 0, 0);
            }
        }
        {
            int ti = 0;
            for (int nt = wave; nt < NT; nt += 4, ++ti)
                for (int i = 0; i < 4; ++i)
                    rec_lds[(lq * 4 + i) * NCP + nt * 16 + l15] = acc[ti][i];
        }
        __syncthreads();

        // 4. gates + state update + outputs + publish
        for (int e = 0; e < ne; ++e) {
            int b = eb[e], co = eco[e], ih = eih[e], gb = egb[e];
            float rz = rec_lds[b * NCP + co] + ebrz[e];
            float rr = rec_lds[b * NCP + HS + co] + ebrr[e];
            float rh = rec_lds[b * NCP + 2 * HS + co] + ebrh[e];
            float z = 1.f / (1.f + __expf(-(xzv[e] + rz)));
            float r = 1.f / (1.f + __expf(-(xrv[e] + rr)));
            float pre = xhv[e] + r * rh;
            float th = 2.f / (1.f + __expf(-2.f * pre)) - 1.f;
            float hn = z * hold[e] + (1.f - z) * th;
            if (tokv[e] == 0) hn = hold[e];            // masked: carry state
            hold[e] = hn;
            u16 hv = f2bf(hn);
            out_f32[((size_t)gb * 256 + t) * UH + ih] = hn;
            if (WB16) out_b16[(size_t)(t * 128 + gb) * UH + ih] = hv;
            if (t == 255) h_final[(size_t)gb * UH + ih] = hn;
            __hip_atomic_store(hdst + b * UH + ih, hv, __ATOMIC_RELAXED,
                               __HIP_MEMORY_SCOPE_AGENT);
        }
        // 5. ensure all our agent-visible stores reached the coherence point,
        //    then publish (no buffer_wbl2 — everything cross-visible was sc1)
        asm volatile("s_waitcnt vmcnt(0)" ::: "memory");
        __syncthreads();
        if (tid == 0)
            __hip_atomic_fetch_add(c, 1, __ATOMIC_RELAXED,
                                   __HIP_MEMORY_SCOPE_AGENT);
    }
}

// ---------------------------------------------------------------------------
// launch
// ---------------------------------------------------------------------------
extern "C" void kernel_launch(void* const* d_in, const int* in_sizes, int n_in,
                              void* d_out, int out_size, void* d_ws, size_t ws_size,
                              hipStream_t stream)
{
    const int*   tokens = (const int*)d_in[0];
    const float* emb    = (const float*)d_in[1];
    const float* gamma  = (const float*)d_in[2];
    const float* beta   = (const float*)d_in[3];
    const float* mmean  = (const float*)d_in[4];
    const float* mvar   = (const float*)d_in[5];
    const float* W1     = (const float*)d_in[6];
    const float* U1     = (const float*)d_in[7];
    const float* b1     = (const float*)d_in[8];
    const float* W2     = (const float*)d_in[9];
    const float* U2     = (const float*)d_in[10];
    const float* b2     = (const float*)d_in[11];

    float* out = (float*)d_out;
    char* ws = (char*)d_ws;

    u16* x     = (u16*)(ws + 0);            // 32768*200*2  = 13,107,200
    u16* xw1   = (u16*)(ws + 13107200);     // 32768*1200*2 = 78,643,200
    u16* o1b   = (u16*)(ws + 91750400);     // 32768*400*2  = 26,214,400
    u16* xw2   = (u16*)(ws + 117964800);    // 32768*600*2  = 39,321,600
    u16* W1T   = (u16*)(ws + 157286400);    // 480,000
    u16* W2T   = (u16*)(ws + 157766400);    // 480,000
    u16* U1T   = (u16*)(ws + 158246400);    // 960,000
    u16* U2T   = (u16*)(ws + 159206400);    // 240,000
    u16* hbuf1 = (u16*)(ws + 159446400);    // 8*2*16*400 u16 = 204,800 B
    u16* hbuf2 = (u16*)(ws + 159651200);    // 8*2*16*200 u16 = 102,400 B
    int* flags = (int*)(ws + 159753600);    // 256 ints (counters, 64B-spaced)

    float* out2 = out;              // [128,256,200]
    float* out1 = out + 6553600;    // [128,256,400]
    float* h2   = out + 19660800;   // [128,200]
    float* h1   = out + 19686400;   // [128,400]

    prep_kernel<<<4521, 256, 0, stream>>>(W1, W2, U1, U2, W1T, W2T, U1T, U2T,
                                          (u32*)hbuf1, flags);
    embed_bn_kernel<<<25600, 256, 0, stream>>>(tokens, emb, gamma, beta, mmean,
                                               mvar, x);
    // xw1 = x @ W1 + bi1   ([32768,200]@[200,1200])
    gemm_bias_kernel<200, 7, 232><<<dim3(512, 19), 256, 0, stream>>>(
        x, W1T, b1, xw1, 1200);
    // GRU1: UH=400, G=16 (128 WGs), KSTEPS=13, KPAD=424, HS=25, NC=75, NCP=80,
    // NT=5, MAXT=2, MAXE=2, write bf16 copy of out1
    gru_kernel<400, 16, 13, 424, 25, 75, 80, 5, 2, 2, true><<<128, 256, 0, stream>>>(
        xw1, U1T, b1 + 1200, tokens, out1, o1b, h1, hbuf1, flags);
    // xw2 = out1 @ W2 + bi2   ([32768,400]@[400,600])
    gemm_bias_kernel<400, 13, 424><<<dim3(512, 10), 256, 0, stream>>>(
        o1b, W2T, b2, xw2, 600);
    // GRU2: UH=200, G=4 (32 WGs), KSTEPS=7, KPAD=232, HS=50, NC=150, NCP=160,
    // NT=10, MAXT=3, MAXE=4
    gru_kernel<200, 4, 7, 232, 50, 150, 160, 10, 3, 4, false><<<32, 256, 0, stream>>>(
        xw2, U2T, b2 + 600, tokens, out2, (u16*)nullptr, h2, hbuf2, flags + 128);
}

// Round 3
// 3567.496 us; speedup vs baseline: 1.6954x; 1.2764x over previous
//
#include <hip/hip_runtime.h>

typedef unsigned int u32;
typedef unsigned short u16;
typedef unsigned long long u64;

typedef __attribute__((ext_vector_type(8))) short bf16x8;
typedef __attribute__((ext_vector_type(4))) float f32x4;

__device__ __forceinline__ u16 f2bf(float f) {
    u32 u = __float_as_uint(f);
    u += 0x7fffu + ((u >> 16) & 1u);
    return (u16)(u >> 16);
}
__device__ __forceinline__ float bf2f(u16 h) {
    return __uint_as_float(((u32)h) << 16);
}

// ---------------------------------------------------------------------------
// prep: convert/transpose weights to bf16, zero tagged h-exchange buffers
// (u32 words, tag 0 == "h_0 available, value 0")
// ---------------------------------------------------------------------------
__global__ __launch_bounds__(256) void prep_kernel(
    const float* __restrict__ W1, const float* __restrict__ W2,
    const float* __restrict__ U1, const float* __restrict__ U2,
    u16* __restrict__ W1T, u16* __restrict__ W2T,
    u16* __restrict__ U1T, u16* __restrict__ U2T,
    u32* __restrict__ hzero)
{
    int i = blockIdx.x * 256 + threadIdx.x;
    if (i < 240000) { int j = i / 200, k = i - j * 200; W1T[i] = f2bf(W1[k * 1200 + j]); return; }
    i -= 240000;
    if (i < 240000) { int j = i / 400, k = i - j * 400; W2T[i] = f2bf(W2[k * 600 + j]); return; }
    i -= 240000;
    if (i < 480000) { int j = i / 400, k = i - j * 400; U1T[i] = f2bf(U1[k * 1200 + j]); return; }
    i -= 480000;
    if (i < 120000) { int j = i / 200, k = i - j * 200; U2T[i] = f2bf(U2[k * 600 + j]); return; }
    i -= 120000;
    if (i < 153600) hzero[i] = 0u;   // both tagged h-exchange buffers
}

// ---------------------------------------------------------------------------
// embed + batchnorm -> x bf16, layout [t*128 + b][200]
// ---------------------------------------------------------------------------
__global__ __launch_bounds__(256) void embed_bn_kernel(
    const int* __restrict__ tokens, const float* __restrict__ emb,
    const float* __restrict__ gamma, const float* __restrict__ beta,
    const float* __restrict__ mmean, const float* __restrict__ mvar,
    u16* __restrict__ x)
{
    int gid = blockIdx.x * 256 + threadIdx.x;  // 6,553,600 total
    int r = gid / 200, e = gid - r * 200;
    int t = r >> 7, b = r & 127;               // r = t*128 + b
    int tok = tokens[b * 256 + t];
    float v = (emb[(size_t)tok * 200 + e] - mmean[e]) *
              (1.0f / sqrtf(mvar[e] + 1e-3f)) * gamma[e] + beta[e];
    x[gid] = f2bf(v);
}

// ---------------------------------------------------------------------------
// GEMM: C[M][N] (bf16) = A[M][KEL] (bf16) @ B[KEL][N] + bias, B given as
// BT[N][KEL]. Tile 64x64 per 256-thread WG; MFMA 16x16x32 bf16.
// ---------------------------------------------------------------------------
template<int KEL, int KSTEPS, int KPAD>
__global__ __launch_bounds__(256) void gemm_bias_kernel(
    const u16* __restrict__ A, const u16* __restrict__ BT,
    const float* __restrict__ bias, u16* __restrict__ C, int N)
{
    __shared__ u16 A_lds[64 * KPAD];
    __shared__ u16 B_lds[64 * KPAD];
    const int m0 = blockIdx.x * 64, n0 = blockIdx.y * 64;
    const int tid = threadIdx.x;
    const int lane = tid & 63, wave = tid >> 6;
    const int l15 = lane & 15, lq = lane >> 4;

    for (int idx = tid; idx < 64 * (KPAD / 2); idx += 256) {
        int row = idx / (KPAD / 2), kp = idx % (KPAD / 2);
        int k = kp * 2;
        u32 va = (k < KEL) ? *(const u32*)(A + (size_t)(m0 + row) * KEL + k) : 0u;
        *(u32*)(A_lds + row * KPAD + k) = va;
        int gn = n0 + row;
        u32 vb = (k < KEL && gn < N) ? *(const u32*)(BT + (size_t)gn * KEL + k) : 0u;
        *(u32*)(B_lds + row * KPAD + k) = vb;
    }
    __syncthreads();

    f32x4 acc[4];
    for (int i = 0; i < 4; ++i) acc[i] = (f32x4){0.f, 0.f, 0.f, 0.f};
    for (int ks = 0; ks < KSTEPS; ++ks) {
        bf16x8 a = *(const bf16x8*)(A_lds + (wave * 16 + l15) * KPAD + ks * 32 + lq * 8);
        for (int nt = 0; nt < 4; ++nt) {
            bf16x8 b = *(const bf16x8*)(B_lds + (nt * 16 + l15) * KPAD + ks * 32 + lq * 8);
            acc[nt] = __builtin_amdgcn_mfma_f32_16x16x32_bf16(a, b, acc[nt], 0, 0, 0);
        }
    }
    for (int nt = 0; nt < 4; ++nt) {
        int col = n0 + nt * 16 + l15;
        if (col < N) {
            float bv = bias[col];
            for (int i = 0; i < 4; ++i) {
                int row = m0 + wave * 16 + lq * 4 + i;
                C[(size_t)row * N + col] = f2bf(acc[nt][i] + bv);
            }
        }
    }
}

// ---------------------------------------------------------------------------
// Persistent GRU scan with SELF-TAGGED h exchange.
// h element published as u32 = (bf16 << 16) | (t+1). Poll IS the load:
// no flags, no counters, no producer-side drain on the critical path.
// WAR safety: a tag-t word is control-dependent on its producer having
// verified ALL tag-(t-1) words, so buffer parity-2 reuse is race-free.
// A vmcnt(0) before the store phase (cold: all prior stores >=1 step old)
// guarantees same-address store-store ordering across parity reuse.
// ---------------------------------------------------------------------------
template<int UH, int G, int KSTEPS, int KPAD, int HS, int NC, int NCP, int NT,
         int MAXT, int MAXE, int NH, bool WB16>
__global__ __launch_bounds__(256) void gru_kernel(
    const u16* __restrict__ xw,      // [256*128][3*UH] bf16 (row = t*128+b)
    const u16* __restrict__ UT,      // [3*UH][UH] bf16 (transposed U)
    const float* __restrict__ br,    // [3*UH] recurrent bias
    const int* __restrict__ tokens,  // [128][256]
    float* __restrict__ out_f32,     // [128][256][UH]
    u16* __restrict__ out_b16,       // [256*128][UH] or unused
    float* __restrict__ h_final,     // [128][UH]
    u32* __restrict__ hbuf)          // [8][2][16][UH] tagged u32
{
    __shared__ u16 U_lds[NCP * KPAD];
    __shared__ u16 h_lds[16 * KPAD];
    __shared__ float rec_lds[16 * NCP];

    const int wg = blockIdx.x;
    const int g = wg / G, w = wg % G;
    const int tid = threadIdx.x;
    const int b0 = g * 16;
    const int lane = tid & 63, wave = tid >> 6;
    const int l15 = lane & 15, lq = lane >> 4;

    // zero LDS (zero-padding of K and column tails)
    for (int i = tid; i < NCP * KPAD / 2; i += 256) ((u32*)U_lds)[i] = 0u;
    for (int i = tid; i < 16 * KPAD / 2; i += 256) ((u32*)h_lds)[i] = 0u;
    __syncthreads();
    // stage U-slice: local col c -> global col j = (c/HS)*UH + w*HS + (c%HS)
    for (int idx = tid; idx < NC * (UH / 2); idx += 256) {
        int c = idx / (UH / 2), kp = idx % (UH / 2);
        int j = (c / HS) * UH + w * HS + (c % HS);
        u32 v = *(const u32*)(UT + (size_t)j * UH + kp * 2);
        *(u32*)(U_lds + c * KPAD + kp * 2) = v;
    }

    // per-thread gate-element mapping (step-invariant)
    int ne = 0;
    int eb[MAXE], eco[MAXE], eih[MAXE], egb[MAXE], exwoff[MAXE];
    float ebrz[MAXE], ebrr[MAXE], ebrh[MAXE], hold[MAXE];
    for (int u = tid; u < 16 * HS; u += 256) {
        int b = u / HS, co = u % HS;
        int ih = w * HS + co;
        eb[ne] = b; eco[ne] = co; eih[ne] = ih; egb[ne] = b0 + b;
        exwoff[ne] = (b0 + b) * 3 * UH;
        ebrz[ne] = br[ih]; ebrr[ne] = br[UH + ih]; ebrh[ne] = br[2 * UH + ih];
        hold[ne] = 0.f;
        ++ne;
    }

    // per-thread poll-slot mapping: slot = pair of u32 h-words
    constexpr int TOT = 16 * UH / 2;   // u64 slots total
    u32 pend0 = 0;
    int soff[NH], loff[NH];
    for (int i = 0; i < NH; ++i) {
        int s = tid + i * 256;
        if (s < TOT) {
            int b = s / (UH / 2), kk = s % (UH / 2);
            soff[i] = b * UH + kk * 2;        // u32 index into hbuf
            loff[i] = b * KPAD + kk * 2;      // u16 index into h_lds
            pend0 |= 1u << i;
        } else { soff[i] = 0; loff[i] = 0; }
    }

    u32* hb = hbuf + (size_t)g * 2 * 16 * UH;

    for (int t = 0; t < 256; ++t) {
        // 1. prefetch gate inputs for this step (independent of peers)
        float xzv[MAXE], xrv[MAXE], xhv[MAXE];
        int tokv[MAXE];
        for (int e = 0; e < ne; ++e) {
            const u16* xrow = xw + (size_t)t * (128 * 3 * UH) + exwoff[e];
            xzv[e] = bf2f(xrow[eih[e]]);
            xrv[e] = bf2f(xrow[UH + eih[e]]);
            xhv[e] = bf2f(xrow[2 * UH + eih[e]]);
            tokv[e] = tokens[egb[e] * 256 + t];
        }

        // 2. poll tagged h_{t-1}: batched loads, check, stage to LDS
        const u32* hsrc = hb + ((t + 1) & 1) * 16 * UH;
        const u32 want = (u32)t & 0xFFFFu;
        u32 pend = pend0;
        while (pend) {
            u64 tmp[NH];
            #pragma unroll
            for (int i = 0; i < NH; ++i)
                if (pend & (1u << i))
                    tmp[i] = __hip_atomic_load((const u64*)(hsrc + soff[i]),
                                               __ATOMIC_RELAXED,
                                               __HIP_MEMORY_SCOPE_AGENT);
            #pragma unroll
            for (int i = 0; i < NH; ++i)
                if (pend & (1u << i)) {
                    u64 v = tmp[i];
                    if ((u32)(v & 0xFFFFu) == want &&
                        ((u32)(v >> 32) & 0xFFFFu) == want) {
                        u32 pk = ((u32)(v >> 16) & 0xFFFFu) | ((u32)(v >> 48) << 16);
                        *(u32*)(h_lds + loff[i]) = pk;
                        pend &= ~(1u << i);
                    }
                }
            if (pend) __builtin_amdgcn_s_sleep(1);
        }
        __syncthreads();

        // 3. rec = h @ U-slice  (MFMA 16x16x32)
        f32x4 acc[MAXT];
        for (int ti = 0; ti < MAXT; ++ti) acc[ti] = (f32x4){0.f, 0.f, 0.f, 0.f};
        for (int ks = 0; ks < KSTEPS; ++ks) {
            bf16x8 a = *(const bf16x8*)(h_lds + l15 * KPAD + ks * 32 + lq * 8);
            int ti = 0;
            for (int nt = wave; nt < NT; nt += 4, ++ti) {
                bf16x8 b = *(const bf16x8*)(U_lds + (nt * 16 + l15) * KPAD + ks * 32 + lq * 8);
                acc[ti] = __builtin_amdgcn_mfma_f32_16x16x32_bf16(a, b, acc[ti], 0, 0, 0);
            }
        }
        {
            int ti = 0;
            for (int nt = wave; nt < NT; nt += 4, ++ti)
                for (int i = 0; i < 4; ++i)
                    rec_lds[(lq * 4 + i) * NCP + nt * 16 + l15] = acc[ti][i];
        }
        __syncthreads();

        // 4. same-address store-order insurance (cold: prior stores are old)
        asm volatile("s_waitcnt vmcnt(0)" ::: "memory");

        // 5. gates + state update + tagged publish + outputs
        u32* hdst = hb + (t & 1) * 16 * UH;
        for (int e = 0; e < ne; ++e) {
            int b = eb[e], co = eco[e], ih = eih[e], gb = egb[e];
            float rz = rec_lds[b * NCP + co] + ebrz[e];
            float rr = rec_lds[b * NCP + HS + co] + ebrr[e];
            float rh = rec_lds[b * NCP + 2 * HS + co] + ebrh[e];
            float z = 1.f / (1.f + __expf(-(xzv[e] + rz)));
            float r = 1.f / (1.f + __expf(-(xrv[e] + rr)));
            float pre = xhv[e] + r * rh;
            float th = 2.f / (1.f + __expf(-2.f * pre)) - 1.f;
            float hn = z * hold[e] + (1.f - z) * th;
            if (tokv[e] == 0) hn = hold[e];            // masked: carry state
            hold[e] = hn;
            u16 hv = f2bf(hn);
            u32 tagged = ((u32)hv << 16) | (u32)(t + 1);
            __hip_atomic_store(hdst + b * UH + ih, tagged, __ATOMIC_RELAXED,
                               __HIP_MEMORY_SCOPE_AGENT);
            out_f32[((size_t)gb * 256 + t) * UH + ih] = hn;
            if (WB16) out_b16[(size_t)(t * 128 + gb) * UH + ih] = hv;
            if (t == 255) h_final[(size_t)gb * UH + ih] = hn;
        }
    }
}

// ---------------------------------------------------------------------------
// launch
// ---------------------------------------------------------------------------
extern "C" void kernel_launch(void* const* d_in, const int* in_sizes, int n_in,
                              void* d_out, int out_size, void* d_ws, size_t ws_size,
                              hipStream_t stream)
{
    const int*   tokens = (const int*)d_in[0];
    const float* emb    = (const float*)d_in[1];
    const float* gamma  = (const float*)d_in[2];
    const float* beta   = (const float*)d_in[3];
    const float* mmean  = (const float*)d_in[4];
    const float* mvar   = (const float*)d_in[5];
    const float* W1     = (const float*)d_in[6];
    const float* U1     = (const float*)d_in[7];
    const float* b1     = (const float*)d_in[8];
    const float* W2     = (const float*)d_in[9];
    const float* U2     = (const float*)d_in[10];
    const float* b2     = (const float*)d_in[11];

    float* out = (float*)d_out;
    char* ws = (char*)d_ws;

    u16* x     = (u16*)(ws + 0);            // 32768*200*2  = 13,107,200
    u16* xw1   = (u16*)(ws + 13107200);     // 32768*1200*2 = 78,643,200
    u16* o1b   = (u16*)(ws + 91750400);     // 32768*400*2  = 26,214,400
    u16* xw2   = (u16*)(ws + 117964800);    // 32768*600*2  = 39,321,600
    u16* W1T   = (u16*)(ws + 157286400);    // 480,000
    u16* W2T   = (u16*)(ws + 157766400);    // 480,000
    u16* U1T   = (u16*)(ws + 158246400);    // 960,000
    u16* U2T   = (u16*)(ws + 159206400);    // 240,000
    u32* hbuf1 = (u32*)(ws + 159446400);    // 8*2*16*400 u32 = 409,600 B
    u32* hbuf2 = (u32*)(ws + 159856000);    // 8*2*16*200 u32 = 204,800 B

    float* out2 = out;              // [128,256,200]
    float* out1 = out + 6553600;    // [128,256,400]
    float* h2   = out + 19660800;   // [128,200]
    float* h1   = out + 19686400;   // [128,400]

    prep_kernel<<<4819, 256, 0, stream>>>(W1, W2, U1, U2, W1T, W2T, U1T, U2T,
                                          hbuf1);
    embed_bn_kernel<<<25600, 256, 0, stream>>>(tokens, emb, gamma, beta, mmean,
                                               mvar, x);
    // xw1 = x @ W1 + bi1   ([32768,200]@[200,1200])
    gemm_bias_kernel<200, 7, 232><<<dim3(512, 19), 256, 0, stream>>>(
        x, W1T, b1, xw1, 1200);
    // GRU1: UH=400, G=16 (128 WGs), HS=25, NT=5, NH=13 (3200 u64 slots)
    gru_kernel<400, 16, 13, 424, 25, 75, 80, 5, 2, 2, 13, true><<<128, 256, 0, stream>>>(
        xw1, U1T, b1 + 1200, tokens, out1, o1b, h1, hbuf1);
    // xw2 = out1 @ W2 + bi2   ([32768,400]@[400,600])
    gemm_bias_kernel<400, 13, 424><<<dim3(512, 10), 256, 0, stream>>>(
        o1b, W2T, b2, xw2, 600);
    // GRU2: UH=200, G=4 (32 WGs), HS=50, NT=10, NH=7 (1600 u64 slots)
    gru_kernel<200, 4, 7, 232, 50, 150, 160, 10, 3, 4, 7, false><<<32, 256, 0, stream>>>(
        xw2, U2T, b2 + 600, tokens, out2, (u16*)nullptr, h2, hbuf2);
}